// Round 1
// baseline (384.174 us; speedup 1.0000x reference)
//
#include <hip/hip_runtime.h>
#include <stdint.h>

#define NN 50000
#define EE 800000
#define DD 128
#define RR 4
#define LL 3
#define NRSEG (NN*RR)                    // 200000 segments (dst*4 + etype)
#define NKB 20                           // K=640 in chunks of 32
#define NB_SCAN ((NRSEG + 1023)/1024)    // 196 scan blocks

typedef _Float16 f16;
typedef _Float16 f16x8 __attribute__((ext_vector_type(8)));
typedef float f32x4 __attribute__((ext_vector_type(4)));

union U32H { uint32_t u; f16 h[2]; };

// ---------------- CSR build ----------------
__global__ __launch_bounds__(256) void k_hist(const int* __restrict__ ei, const int* __restrict__ et,
                                              int* __restrict__ cnt){
  int e = blockIdx.x*256 + threadIdx.x;
  if(e < EE) atomicAdd(&cnt[ei[EE+e]*RR + et[e]], 1);
}

__global__ __launch_bounds__(256) void k_reduce(const int* __restrict__ cnt, int* __restrict__ bsum){
  __shared__ int s[256];
  int b = blockIdx.x, t = threadIdx.x;
  int base = b*1024 + t*4;
  int v = 0;
  #pragma unroll
  for(int j=0;j<4;j++){ int i = base+j; if(i<NRSEG) v += cnt[i]; }
  s[t]=v; __syncthreads();
  for(int o=128;o>0;o>>=1){ if(t<o) s[t]+=s[t+o]; __syncthreads(); }
  if(t==0) bsum[b]=s[0];
}

__global__ __launch_bounds__(256) void k_top(const int* __restrict__ bsum, int* __restrict__ boff,
                                             int* __restrict__ rowp, int nb){
  __shared__ int s[256];
  int t=threadIdx.x;
  int v = (t<nb)? bsum[t] : 0;
  s[t]=v; __syncthreads();
  for(int o=1;o<256;o<<=1){ int x=(t>=o)?s[t-o]:0; __syncthreads(); s[t]+=x; __syncthreads(); }
  if(t<nb) boff[t] = s[t]-v;
  if(t==255) rowp[NRSEG] = s[255];
}

__global__ __launch_bounds__(256) void k_scan(const int* __restrict__ cnt, const int* __restrict__ boff,
                                              int* __restrict__ rowp, float* __restrict__ inv){
  __shared__ int s[256];
  int b=blockIdx.x, t=threadIdx.x;
  int base = b*1024 + t*4;
  int c[4]; int tot=0;
  #pragma unroll
  for(int j=0;j<4;j++){ int i=base+j; c[j] = (i<NRSEG)? cnt[i]:0; tot+=c[j]; }
  s[t]=tot; __syncthreads();
  for(int o=1;o<256;o<<=1){ int x=(t>=o)?s[t-o]:0; __syncthreads(); s[t]+=x; __syncthreads(); }
  int run = boff[b] + s[t]-tot;
  #pragma unroll
  for(int j=0;j<4;j++){
    int i=base+j;
    if(i<NRSEG){ rowp[i]=run; inv[i] = 1.0f/(float)max(c[j],1); run+=c[j]; }
  }
}

__global__ __launch_bounds__(256) void k_scatter(const int* __restrict__ ei, const int* __restrict__ et,
                                                 int* __restrict__ cursor, int* __restrict__ ssrc){
  int e = blockIdx.x*256 + threadIdx.x;
  if(e < EE){
    int seg = ei[EE+e]*RR + et[e];
    int p = atomicAdd(&cursor[seg], 1);
    ssrc[p] = ei[e];
  }
}

// ---------------- dtype converts ----------------
// Wf fragment-order: t = ((l*NKB+kb)*8+cb)*64+lane, 8 halves each:
//   Wf[t*8+e] = Wcat[k = kb*32 + (lane>>4)*8 + e][col = cb*16 + (lane&15)]
__global__ __launch_bounds__(256) void k_wconv(const float* __restrict__ W, const float* __restrict__ root,
                                               f16* __restrict__ Wf){
  int t = blockIdx.x*256 + threadIdx.x;
  if(t >= LL*NKB*8*64) return;
  int lane = t & 63;
  int cb   = (t>>6) & 7;
  int kb   = (t>>9) % NKB;
  int l    = (t>>9) / NKB;
  int col  = cb*16 + (lane&15);
  int kbase= kb*32 + (lane>>4)*8;
  f16* dst = Wf + (size_t)t*8;
  #pragma unroll
  for(int e=0;e<8;e++){
    int k = kbase+e;
    float v = (k < 4*DD) ? W[(((size_t)l*RR + (k>>7))*DD + (k&127))*DD + col]
                         : root[((size_t)l*DD + (k-4*DD))*DD + col];
    dst[e] = (f16)v;
  }
}

__global__ __launch_bounds__(256) void k_xconv(const float* __restrict__ x, f16* __restrict__ x16){
  int t = blockIdx.x*256 + threadIdx.x;
  if(t < NN*DD) x16[t] = (f16)x[t];
}

// ---------------- aggregation: one wave per dst node ----------------
__global__ __launch_bounds__(256) void k_agg(const f16* __restrict__ x16, const int* __restrict__ rowp,
                                             const int* __restrict__ ssrc, const float* __restrict__ inv,
                                             f16* __restrict__ A16){
  int gid  = (blockIdx.x*256 + threadIdx.x) >> 6;   // dst node
  int lane = threadIdx.x & 63;
  if(gid >= NN) return;
  const uint32_t* xu = (const uint32_t*)x16;
  uint32_t* au = (uint32_t*)A16;
  #pragma unroll
  for(int r=0;r<RR;r++){
    int seg = gid*RR + r;
    int b = rowp[seg], e = rowp[seg+1];
    float ax=0.f, ay=0.f;
    int i=b;
    for(; i+1<e; i+=2){
      int s0 = ssrc[i], s1 = ssrc[i+1];
      U32H v0, v1; v0.u = xu[(size_t)s0*64 + lane]; v1.u = xu[(size_t)s1*64 + lane];
      ax += (float)v0.h[0] + (float)v1.h[0];
      ay += (float)v0.h[1] + (float)v1.h[1];
    }
    if(i<e){
      U32H v; v.u = xu[(size_t)ssrc[i]*64 + lane];
      ax += (float)v.h[0]; ay += (float)v.h[1];
    }
    float sc = inv[seg];
    U32H o; o.h[0] = (f16)(ax*sc); o.h[1] = (f16)(ay*sc);
    au[(size_t)seg*64 + lane] = o.u;
  }
}

// ---------------- GEMM (M=NN, K=640, N=128) + fused epilogue ----------------
// Block = 128 threads (2 waves), BM=64 rows; wave owns 32 rows x 128 cols.
__device__ __forceinline__ void stageB(const f16* __restrict__ Wf, f16* lds, int kb, int wid, int lane){
  const f16* src = Wf + (size_t)kb*4096;
  #pragma unroll
  for(int j=wid;j<8;j+=2){
    __builtin_amdgcn_global_load_lds((const __attribute__((address_space(1))) void*)(src + j*512 + lane*8),
                                     (__attribute__((address_space(3))) void*)(lds + j*512), 16, 0, 0);
  }
}

template<int LAST>
__global__ __launch_bounds__(128) void k_gemm(const f16* __restrict__ A16, const f16* __restrict__ x16,
                                              const f16* __restrict__ Wf,
                                              const float* __restrict__ bias, const float* __restrict__ gmm,
                                              const float* __restrict__ bet,
                                              f16* __restrict__ xnext, float* __restrict__ outf){
  __shared__ f16 Blds[2][4096];   // [buf][cb*512 + lane*8 + e]
  int tid  = threadIdx.x;
  int lane = tid & 63, wid = tid >> 6;
  int rbase = blockIdx.x*64 + wid*32;           // this wave's first row
  int fr = lane & 15, kg = lane >> 4;

  int arow0 = rbase + fr;       if(arow0 >= NN) arow0 = NN-1;
  int arow1 = rbase + 16 + fr;  if(arow1 >= NN) arow1 = NN-1;
  const f16* Ar0 = A16 + (size_t)arow0*512 + kg*8;
  const f16* Ar1 = A16 + (size_t)arow1*512 + kg*8;
  const f16* Xr0 = x16 + (size_t)arow0*128 + kg*8;
  const f16* Xr1 = x16 + (size_t)arow1*128 + kg*8;

  f32x4 acc[2][8];
  #pragma unroll
  for(int r=0;r<2;r++)
    #pragma unroll
    for(int c=0;c<8;c++) acc[r][c] = (f32x4){0.f,0.f,0.f,0.f};

  f16x8 a0, a1;
  a0 = *(const f16x8*)(Ar0); a1 = *(const f16x8*)(Ar1);
  stageB(Wf, &Blds[0][0], 0, wid, lane);

  for(int kb=0; kb<NKB; kb++){
    __syncthreads();                                   // stage(kb) done, prev reads done
    if(kb+1 < NKB) stageB(Wf, &Blds[(kb+1)&1][0], kb+1, wid, lane);
    f16x8 na0 = a0, na1 = a1;
    if(kb+1 < NKB){
      if(kb+1 < 16){ na0 = *(const f16x8*)(Ar0 + (kb+1)*32); na1 = *(const f16x8*)(Ar1 + (kb+1)*32); }
      else         { na0 = *(const f16x8*)(Xr0 + (kb+1-16)*32); na1 = *(const f16x8*)(Xr1 + (kb+1-16)*32); }
    }
    const f16* bb = &Blds[kb&1][lane*8];
    #pragma unroll
    for(int cb=0;cb<8;cb++){
      f16x8 b = *(const f16x8*)(bb + cb*512);
      acc[0][cb] = __builtin_amdgcn_mfma_f32_16x16x32_f16(a0, b, acc[0][cb], 0, 0, 0);
      acc[1][cb] = __builtin_amdgcn_mfma_f32_16x16x32_f16(a1, b, acc[1][cb], 0, 0, 0);
    }
    a0 = na0; a1 = na1;
  }

  // epilogue: bias -> relu -> +residual -> LayerNorm  (C/D: col=lane&15, row=(lane>>4)*4+q)
  float bs[8];
  #pragma unroll
  for(int cb=0;cb<8;cb++) bs[cb] = bias[cb*16 + fr];
  int g4 = kg*4;
  #pragma unroll
  for(int rh=0; rh<2; rh++){
    float vv[8][4];
    #pragma unroll
    for(int cb=0;cb<8;cb++){
      int col = cb*16 + fr;
      #pragma unroll
      for(int q=0;q<4;q++){
        float v = acc[rh][cb][q] + bs[cb];
        v = v > 0.f ? v : 0.f;
        int row = rbase + rh*16 + g4 + q;
        float res = (row < NN) ? (float)x16[(size_t)row*128 + col] : 0.f;
        vv[cb][q] = v + res;
      }
    }
    #pragma unroll
    for(int q=0;q<4;q++){
      float s1=0.f, s2=0.f;
      #pragma unroll
      for(int cb=0;cb<8;cb++){ float v=vv[cb][q]; s1+=v; s2+=v*v; }
      #pragma unroll
      for(int m=1;m<16;m<<=1){ s1 += __shfl_xor(s1,m,16); s2 += __shfl_xor(s2,m,16); }
      float mu  = s1*(1.f/128.f);
      float var = s2*(1.f/128.f) - mu*mu;
      float rs  = rsqrtf(var + 1e-5f);
      int row = rbase + rh*16 + g4 + q;
      if(row < NN){
        #pragma unroll
        for(int cb=0;cb<8;cb++){
          int col = cb*16 + fr;
          float y = (vv[cb][q]-mu)*rs*gmm[col] + bet[col];
          if(LAST) outf[(size_t)row*128 + col] = y;
          else     xnext[(size_t)row*128 + col] = (f16)y;
        }
      }
    }
  }
}

// ---------------- launch ----------------
extern "C" void kernel_launch(void* const* d_in, const int* in_sizes, int n_in,
                              void* d_out, int out_size, void* d_ws, size_t ws_size,
                              hipStream_t stream){
  const float* x    = (const float*)d_in[0];
  const int*   ei   = (const int*)d_in[1];
  const int*   et   = (const int*)d_in[2];
  const float* W    = (const float*)d_in[3];
  const float* root = (const float*)d_in[4];
  const float* bias = (const float*)d_in[5];
  const float* gmm  = (const float*)d_in[6];
  const float* bet  = (const float*)d_in[7];

  char* ws = (char*)d_ws;
  int*   cnt  = (int*)(ws + 0);            // 800000 B (reused as scatter cursor)
  int*   rowp = (int*)(ws + 800768);       // 800004 B
  float* inv  = (float*)(ws + 1601536);    // 800000 B
  int*   ssrc = (int*)(ws + 2402304);      // 3.2 MB
  int*   bsum = (int*)(ws + 5602304);      // 1 KB
  int*   boff = (int*)(ws + 5603328);      // 1 KB
  f16*   Wf   = (f16*)(ws + 5604352);      // 491520 B
  f16*   x16a = (f16*)(ws + 6095872);      // 12.8 MB
  f16*   x16b = (f16*)(ws + 18895872);     // 12.8 MB
  f16*   A16  = (f16*)(ws + 31695872);     // 51.2 MB   (total ~82.9 MB)

  hipMemsetAsync(cnt, 0, NRSEG*4, stream);
  k_hist   <<<(EE+255)/256, 256, 0, stream>>>(ei, et, cnt);
  k_reduce <<<NB_SCAN, 256, 0, stream>>>(cnt, bsum);
  k_top    <<<1, 256, 0, stream>>>(bsum, boff, rowp, NB_SCAN);
  k_scan   <<<NB_SCAN, 256, 0, stream>>>(cnt, boff, rowp, inv);
  hipMemcpyAsync(cnt, rowp, NRSEG*4, hipMemcpyDeviceToDevice, stream);
  k_scatter<<<(EE+255)/256, 256, 0, stream>>>(ei, et, cnt, ssrc);
  k_wconv  <<<(LL*NKB*8*64+255)/256, 256, 0, stream>>>(W, root, Wf);
  k_xconv  <<<(NN*DD)/256, 256, 0, stream>>>(x, x16a);

  f16* xc = x16a; f16* xn = x16b;
  for(int l=0; l<LL; l++){
    k_agg<<<(NN+3)/4, 256, 0, stream>>>(xc, rowp, ssrc, inv, A16);
    if(l < LL-1)
      k_gemm<0><<<(NN+63)/64, 128, 0, stream>>>(A16, xc, Wf + (size_t)l*81920,
                                                bias+l*DD, gmm+l*DD, bet+l*DD, xn, nullptr);
    else
      k_gemm<1><<<(NN+63)/64, 128, 0, stream>>>(A16, xc, Wf + (size_t)l*81920,
                                                bias+l*DD, gmm+l*DD, bet+l*DD, nullptr, (float*)d_out);
    f16* t = xc; xc = xn; xn = t;
  }
}